// Round 6
// baseline (116.560 us; speedup 1.0000x reference)
//
#include <hip/hip_runtime.h>
#include <stdint.h>

#define Hh 192
#define Ww 192
#define HW 36864            // 192*192
#define CROPW 38
#define CW2 1444            // 38*38
#define CROPOFF 77
#define NPTS 11552          // 8*38*38
#define NPAD 11776          // 46*256
#define NTT 46              // 256-row tiles
#define NCT 92              // 128-col tiles
#define NG 5                // col-tile groups
#define JPB 19              // col-tiles per group (last group gets 16)
#define NBLK (NG*NTT)       // 230 persistent blocks
#define TRB (HW/32)         // 1152 transpose blocks per batch
#define BIGF 3.0e38f

typedef short bf16x8 __attribute__((ext_vector_type(8)));
typedef float f32x4 __attribute__((ext_vector_type(4)));
typedef int   i32x4 __attribute__((ext_vector_type(4)));
typedef unsigned short ushort;

__device__ __forceinline__ ushort f2bf(float f) {
  uint32_t b = __float_as_uint(f);
  uint32_t r = b + 0x7fffu + ((b >> 16) & 1u);
  return (ushort)(r >> 16);
}
__device__ __forceinline__ float bf2f(ushort u) {
  return __uint_as_float(((uint32_t)u) << 16);
}

// ---- fused: transpose feat2 (B,C,H,W)f32 -> f2t (B,H,W,C)bf16  AND feat1 crop ----
__global__ __launch_bounds__(256) void prep_k(
    const float* __restrict__ feat1, const float* __restrict__ feat2,
    ushort* __restrict__ f2t, ushort* __restrict__ aB, float* __restrict__ d1) {
  __shared__ __align__(16) ushort lsh[38*136];
  int b = blockIdx.y;
  int t = threadIdx.x;
  if (blockIdx.x < TRB) {
    // ---------------- transpose tile: 32 hw-positions x 128 channels ----------
    int hw0 = blockIdx.x * 32;
    {
      int i4 = (t & 7) * 4, c0 = t >> 3;
      const float* src = feat2 + (size_t)b*128*HW + hw0 + i4;
      #pragma unroll
      for (int k = 0; k < 4; ++k) {
        int cc = c0 + k*32;
        f32x4 v = *(const f32x4*)(src + (size_t)cc*HW);
        #pragma unroll
        for (int j = 0; j < 4; ++j) lsh[(i4+j)*136 + cc] = f2bf(v[j]);
      }
    }
    __syncthreads();
    {
      int chunk = t & 7, p = t >> 3;
      ushort* dst = f2t + ((size_t)b*HW + hw0 + p)*128 + chunk*16;
      *(bf16x8*)dst       = *(const bf16x8*)&lsh[p*136 + chunk*16];
      *(bf16x8*)(dst + 8) = *(const bf16x8*)&lsh[p*136 + chunk*16 + 8];
    }
  } else {
    // ---------------- crop row: feat1 -> aB (channel-last bf16) + d1 ----------
    int r = blockIdx.x - TRB;          // 0..37
    int y = CROPOFF + r;
    {
      int xo = t & 63, c0 = t >> 6;
      if (xo < CROPW) {
        const float* src = feat1 + ((size_t)b*128*HW) + (size_t)y*Ww + CROPOFF + xo;
        #pragma unroll
        for (int k = 0; k < 32; ++k) {
          int cc = c0*32 + k;
          lsh[xo*136 + cc] = f2bf(src[(size_t)cc*HW]);
        }
      }
    }
    __syncthreads();
    int chunk = t & 7, p0 = t >> 3;
    #pragma unroll
    for (int pp = 0; pp < 2; ++pp) {
      int p = p0 + pp*32;
      if (p >= CROPW) break;
      int idx = b*CW2 + r*CROPW + p;
      ushort* dst = aB + (size_t)idx*128 + chunk*16;
      *(bf16x8*)dst       = *(const bf16x8*)&lsh[p*136 + chunk*16];
      *(bf16x8*)(dst + 8) = *(const bf16x8*)&lsh[p*136 + chunk*16 + 8];
      float s = 0.f;
      #pragma unroll
      for (int j = 0; j < 16; ++j) {
        float v = bf2f(lsh[p*136 + chunk*16 + j]);
        s += v*v;
      }
      s += __shfl_xor(s, 1); s += __shfl_xor(s, 2); s += __shfl_xor(s, 4);
      if (chunk == 0) d1[idx] = s;
    }
  }
}

// ---- sample: 1 wave = 1 point, lane = 2 channels; last block inits pads ------
__global__ __launch_bounds__(256) void samp2_k(
    const ushort* __restrict__ f2t, const float* __restrict__ aflow,
    ushort* __restrict__ pB, float* __restrict__ d2) {
  int tid = threadIdx.x;
  if (blockIdx.x == NPTS/4) {          // pad init: pB rows + d2 sentinels
    int i = NPTS + tid;
    if (i < NPAD) {
      d2[i] = 1e30f;
      i32x4 z = {0,0,0,0};
      #pragma unroll
      for (int c = 0; c < 16; ++c) *(i32x4*)&pB[(size_t)i*128 + c*8] = z;
    }
    return;
  }
  int idx = blockIdx.x*4 + (tid >> 6);
  int l = tid & 63, c2 = l*2;
  int b = idx / CW2;
  int rem = idx % CW2;
  int r = rem / CROPW, cx = rem % CROPW;
  int y = CROPOFF + r, x = CROPOFF + cx;

  float ax = aflow[((b*2 + 0)*Hh + y)*Ww + x];
  float ay = aflow[((b*2 + 1)*Hh + y)*Ww + x];
  float gxn = ax * (2.0f/(Ww-1)) - 1.0f;
  float gyn = ay * (2.0f/(Hh-1)) - 1.0f;
  float gx = (gxn + 1.0f) * 0.5f * (Ww-1);
  float gy = (gyn + 1.0f) * 0.5f * (Hh-1);
  int xi = min((int)floorf(gx), Ww-2);
  int yi = min((int)floorf(gy), Hh-2);
  float wx1 = gx - (float)xi, wx0 = 1.f - wx1;
  float wy1 = gy - (float)yi, wy0 = 1.f - wy1;

  const ushort* base = f2t + ((size_t)b*HW + (size_t)yi*Ww + xi)*128 + c2;
  uint32_t u00 = *(const uint32_t*)(base);
  uint32_t u01 = *(const uint32_t*)(base + 128);
  uint32_t u10 = *(const uint32_t*)(base + Ww*128);
  uint32_t u11 = *(const uint32_t*)(base + Ww*128 + 128);
  float v0 = wy0*(wx0*bf2f((ushort)u00) + wx1*bf2f((ushort)u01))
           + wy1*(wx0*bf2f((ushort)u10) + wx1*bf2f((ushort)u11));
  float v1 = wy0*(wx0*bf2f((ushort)(u00>>16)) + wx1*bf2f((ushort)(u01>>16)))
           + wy1*(wx0*bf2f((ushort)(u10>>16)) + wx1*bf2f((ushort)(u11>>16)));

  uint32_t packed = ((uint32_t)f2bf(v1) << 16) | f2bf(v0);
  *(uint32_t*)&pB[(size_t)idx*128 + c2] = packed;

  float s = v0*v0 + v1*v1;
  for (int off = 1; off < 64; off <<= 1) s += __shfl_xor(s, off);
  if (l == 0) d2[idx] = s;
}

// ---- persistent fused GEMM: A-frags in REGISTERS, B read direct from L2 ------
// No LDS staging, no swizzle, no barriers in the main loop. Wave tile 128Mx32N
// (2wr x 4wc waves), A hoisted once (32 dwordx4, coalesced 16rows x 64B), B
// fragments read per iter from L2-resident pB (per-XCD stripe ~600KB).
// Swapped MFMA: anchor index in lane&15; row-min in t-space in registers.
__global__ __launch_bounds__(512, 2) void gemmp_k(
    const ushort* __restrict__ aB, const ushort* __restrict__ pB,
    const float* __restrict__ d1, const float* __restrict__ d2,
    float* __restrict__ pos, float* __restrict__ pmin) {
  __shared__ float sm[4][256];          // final cross-wave reduce only (4 KB)

  // m204 bijective chunked XCD swizzle: nwg=230, q=28, r=6
  int bid = blockIdx.x;
  int xcd = bid & 7, kk = bid >> 3;
  int start = (xcd < 6) ? xcd*29 : 174 + (xcd-6)*28;
  int L = start + kk;
  int g = L / NTT, tM = L % NTT;
  int j0 = g * JPB;
  int jn = (NCT - j0 < JPB) ? (NCT - j0) : JPB;

  int tid = threadIdx.x;
  int w = tid >> 6, l = tid & 63;
  int wr = w >> 2, wc = w & 3;          // wave tile: 128 M x 32 N
  int lcol = l & 15, hq = l >> 4, rb = hq << 2;

  // hoist A fragments: row = tM*256 + wr*128 + ma*16 + lcol, bytes ks*64+hq*16
  bf16x8 aF[32];                        // [ma*4+ks], 128 VGPR
  {
    const char* gA = (const char*)aB + ((size_t)(tM*256 + wr*128 + lcol))*256 + hq*16;
    #pragma unroll
    for (int ma = 0; ma < 8; ++ma)
      #pragma unroll
      for (int ks = 0; ks < 4; ++ks)
        aF[ma*4+ks] = *(const bf16x8*)(gA + ma*16*256 + ks*64);
  }

  float mPart[8] = {BIGF,BIGF,BIGF,BIGF,BIGF,BIGF,BIGF,BIGF};

  for (int it = 0; it < jn; ++it) {
    int j = j0 + it;
    const char* gB = (const char*)pB + ((size_t)(j*128 + wc*32 + lcol))*256 + hq*16;
    f32x4 acc[2][8] = {};               // [np][ma]
    #pragma unroll
    for (int ks = 0; ks < 4; ++ks) {
      bf16x8 b0 = *(const bf16x8*)(gB + ks*64);
      bf16x8 b1 = *(const bf16x8*)(gB + 16*256 + ks*64);
      #pragma unroll
      for (int ma = 0; ma < 8; ++ma)
        acc[0][ma] = __builtin_amdgcn_mfma_f32_16x16x32_bf16(b0, aF[ma*4+ks], acc[0][ma], 0, 0, 0);
      #pragma unroll
      for (int ma = 0; ma < 8; ++ma)
        acc[1][ma] = __builtin_amdgcn_mfma_f32_16x16x32_bf16(b1, aF[ma*4+ks], acc[1][ma], 0, 0, 0);
    }

    f32x4 d2v0 = *(const f32x4*)&d2[j*128 + wc*32 + rb];
    f32x4 d2v1 = *(const f32x4*)&d2[j*128 + wc*32 + 16 + rb];

    if ((j >> 1) != tM) {               // non-diagonal col-tile (uniform branch)
      #pragma unroll
      for (int ma = 0; ma < 8; ++ma) {
        #pragma unroll
        for (int reg = 0; reg < 4; ++reg) {
          mPart[ma] = fminf(mPart[ma], fmaf(-2.f, acc[0][ma][reg], d2v0[reg]));
          mPart[ma] = fminf(mPart[ma], fmaf(-2.f, acc[1][ma][reg], d2v1[reg]));
        }
      }
    } else {                            // diagonal-overlapping tile
      #pragma unroll
      for (int ma = 0; ma < 8; ++ma) {
        int gi = tM*256 + wr*128 + ma*16 + lcol;
        #pragma unroll
        for (int np = 0; np < 2; ++np) {
          #pragma unroll
          for (int reg = 0; reg < 4; ++reg) {
            int gj = j*128 + wc*32 + np*16 + rb + reg;
            float t = fmaf(-2.f, acc[np][ma][reg], np ? d2v1[reg] : d2v0[reg]);
            if (gi == gj)
              pos[gi] = sqrtf(fmaxf(d1[gi] + t, 0.f) + 1e-6f) + 1e-8f;
            else
              mPart[ma] = fminf(mPart[ma], t);
          }
        }
      }
    }
  }

  // reduce over hq lanes, then over the 4 wc waves via small LDS
  #pragma unroll
  for (int ma = 0; ma < 8; ++ma) {
    float u = mPart[ma];
    u = fminf(u, __shfl_xor(u, 16));
    u = fminf(u, __shfl_xor(u, 32));
    mPart[ma] = u;
  }
  if (hq == 0) {
    #pragma unroll
    for (int ma = 0; ma < 8; ++ma)
      sm[wc][wr*128 + ma*16 + lcol] = mPart[ma];
  }
  __syncthreads();
  if (tid < 256) {
    int row = tM*256 + tid;
    float u = fminf(fminf(sm[0][tid], sm[1][tid]), fminf(sm[2][tid], sm[3][tid]));
    pmin[g*NPAD + row] = sqrtf(fmaxf(d1[row] + u, 0.f) + 1e-6f) + 1e-8f;
  }
}

// -------- finalize: min over group partials (+ diag+10 cand), mean relu --------
__global__ __launch_bounds__(1024) void fin_k(const float* __restrict__ pos,
                                              const float* __restrict__ pmin,
                                              float* __restrict__ out) {
  float s = 0.f;
  for (int i = threadIdx.x; i < NPTS; i += 1024) {
    float p = pos[i];
    float mneg = p + 10.f;              // diagonal's +10-modified candidate
    #pragma unroll
    for (int g = 0; g < NG; ++g) mneg = fminf(mneg, pmin[g*NPAD + i]);
    s += fmaxf(1.0f + p - mneg, 0.f);
  }
  for (int off = 1; off < 64; off <<= 1) s += __shfl_xor(s, off);
  __shared__ float red[16];
  if ((threadIdx.x & 63) == 0) red[threadIdx.x >> 6] = s;
  __syncthreads();
  if (threadIdx.x == 0) {
    float t = 0.f;
    #pragma unroll
    for (int k = 0; k < 16; ++k) t += red[k];
    out[0] = t / (float)NPTS;
  }
}

extern "C" void kernel_launch(void* const* d_in, const int* in_sizes, int n_in,
                              void* d_out, int out_size, void* d_ws, size_t ws_size,
                              hipStream_t stream) {
  const float* feat1 = (const float*)d_in[0];
  const float* feat2 = (const float*)d_in[1];
  const float* aflow = (const float*)d_in[2];

  char* ws = (char*)d_ws;
  ushort* aB = (ushort*)ws;                                   // NPAD*128 bf16
  ushort* pB = aB + (size_t)NPAD * 128;                       // NPAD*128 bf16
  float*  d1 = (float*)(pB + (size_t)NPAD * 128);             // NPAD f32
  float*  d2 = d1 + NPAD;
  float*  pos = d2 + NPAD;
  float*  pmin = pos + NPAD;                                  // NG*NPAD f32
  ushort* f2t = (ushort*)(pmin + (size_t)NG*NPAD);            // 8*HW*128 bf16

  hipLaunchKernelGGL(prep_k, dim3(TRB + CROPW, 8), dim3(256), 0, stream,
                     feat1, feat2, f2t, aB, d1);
  hipLaunchKernelGGL(samp2_k, dim3(NPTS/4 + 1), dim3(256), 0, stream,
                     f2t, aflow, pB, d2);
  hipLaunchKernelGGL(gemmp_k, dim3(NBLK), dim3(512), 0, stream,
                     aB, pB, d1, d2, pos, pmin);
  hipLaunchKernelGGL(fin_k, dim3(1), dim3(1024), 0, stream,
                     pos, pmin, (float*)d_out);
}

// Round 7
// 98.189 us; speedup vs baseline: 1.1871x; 1.1871x over previous
//
#include <hip/hip_runtime.h>
#include <stdint.h>

#define Hh 192
#define Ww 192
#define HW 36864            // 192*192
#define CROPW 38
#define CW2 1444            // 38*38
#define CROPOFF 77
#define NPTS 11552          // 8*38*38
#define NPAD 11776          // 46*256
#define NTT 46              // 256-row tiles
#define NCT 92              // 128-col tiles
#define NG 5                // col-tile groups
#define JPB 19              // col-tiles per group (last group gets 16)
#define NBLK (NG*NTT)       // 230 persistent blocks
#define CROPB 304           // 38*8 crop blocks
#define CRDB 46             // coord blocks (46*256 >= NPTS)
#define BIGF 3.0e38f

typedef short bf16x8 __attribute__((ext_vector_type(8)));
typedef float f32x4 __attribute__((ext_vector_type(4)));
typedef uint32_t u32x2 __attribute__((ext_vector_type(2)));
typedef uint32_t u32x4 __attribute__((ext_vector_type(4)));
typedef unsigned short ushort;

__device__ __forceinline__ ushort f2bf(float f) {
  uint32_t b = __float_as_uint(f);
  uint32_t r = b + 0x7fffu + ((b >> 16) & 1u);
  return (ushort)(r >> 16);
}
__device__ __forceinline__ float bf2f(ushort u) {
  return __uint_as_float(((uint32_t)u) << 16);
}

__device__ __forceinline__ void g2l16(const void* g, void* l) {
  __builtin_amdgcn_global_load_lds(
      (const __attribute__((address_space(1))) unsigned int*)g,
      (__attribute__((address_space(3))) unsigned int*)l, 16, 0, 0);
}

// ---- prep: feat1 crop -> aB (channel-last bf16)  AND  sample-coord precompute ----
__global__ __launch_bounds__(256) void prep2_k(
    const float* __restrict__ feat1, const float* __restrict__ aflow,
    ushort* __restrict__ aB, u32x4* __restrict__ coords) {
  int bid = blockIdx.x;
  int t = threadIdx.x;
  if (bid < CROPB) {
    // ---------- crop row: feat1 -> aB (channel-last bf16) ----------
    __shared__ __align__(16) ushort lsh[38*136];
    int b = bid / CROPW, r = bid % CROPW;
    int y = CROPOFF + r;
    {
      int xo = t & 63, c0 = t >> 6;
      if (xo < CROPW) {
        const float* src = feat1 + ((size_t)b*128*HW) + (size_t)y*Ww + CROPOFF + xo;
        #pragma unroll
        for (int k = 0; k < 32; ++k) {
          int cc = c0*32 + k;
          lsh[xo*136 + cc] = f2bf(src[(size_t)cc*HW]);
        }
      }
    }
    __syncthreads();
    int chunk = t & 7, p0 = t >> 3;
    #pragma unroll
    for (int pp = 0; pp < 2; ++pp) {
      int p = p0 + pp*32;
      if (p >= CROPW) break;
      int idx = b*CW2 + r*CROPW + p;
      ushort* dst = aB + (size_t)idx*128 + chunk*16;
      *(bf16x8*)dst       = *(const bf16x8*)&lsh[p*136 + chunk*16];
      *(bf16x8*)(dst + 8) = *(const bf16x8*)&lsh[p*136 + chunk*16 + 8];
    }
  } else {
    // ---------- coords: per point, bilinear cell + fractional weights ----------
    int idx = (bid - CROPB)*256 + t;
    if (idx >= NPTS) return;
    int b = idx / CW2;
    int rem = idx % CW2;
    int r = rem / CROPW, cx = rem % CROPW;
    int y = CROPOFF + r, x = CROPOFF + cx;
    float ax = aflow[((b*2 + 0)*Hh + y)*Ww + x];
    float ay = aflow[((b*2 + 1)*Hh + y)*Ww + x];
    // replicate reference's normalize->denormalize round trip
    float gxn = ax * (2.0f/(Ww-1)) - 1.0f;
    float gyn = ay * (2.0f/(Hh-1)) - 1.0f;
    float gx = (gxn + 1.0f) * 0.5f * (Ww-1);
    float gy = (gyn + 1.0f) * 0.5f * (Hh-1);
    // clamp base cell to 190: gx==191 shifts weight to the x=191 tap (identical)
    int xi = min((int)floorf(gx), Ww-2);
    int yi = min((int)floorf(gy), Hh-2);
    u32x4 cd;
    cd.x = (uint32_t)(yi*Ww + xi);
    cd.y = __float_as_uint(gx - (float)xi);
    cd.z = __float_as_uint(gy - (float)yi);
    cd.w = 0;
    coords[idx] = cd;
  }
}

// ---- channel-slab sampler: block=(b,c); plane staged to LDS bf16, gather all pts ----
__global__ __launch_bounds__(256) void slab_k(
    const float* __restrict__ feat2, const u32x4* __restrict__ coords,
    ushort* __restrict__ pB) {
  __shared__ __align__(16) ushort plane[HW];   // 73.7 KB -> 2 blocks/CU
  int bid = blockIdx.x;
  int b = bid >> 7, c = bid & 127;
  int t = threadIdx.x;
  const float* src = feat2 + ((size_t)(b*128 + c)) * HW;
  #pragma unroll
  for (int k = 0; k < 36; ++k) {
    int i = (k*256 + t) * 4;
    f32x4 v = *(const f32x4*)(src + i);
    u32x2 pk;
    pk.x = (uint32_t)f2bf(v[0]) | ((uint32_t)f2bf(v[1]) << 16);
    pk.y = (uint32_t)f2bf(v[2]) | ((uint32_t)f2bf(v[3]) << 16);
    *(u32x2*)&plane[i] = pk;
  }
  __syncthreads();
  int pbase = b*CW2;
  #pragma unroll
  for (int it = 0; it < 6; ++it) {
    int p = it*256 + t;
    if (p < CW2) {
      u32x4 cd = coords[pbase + p];
      int cell = (int)cd.x;
      float wx1 = __uint_as_float(cd.y), wx0 = 1.f - wx1;
      float wy1 = __uint_as_float(cd.z), wy0 = 1.f - wy1;
      float v00 = bf2f(plane[cell]);
      float v01 = bf2f(plane[cell + 1]);
      float v10 = bf2f(plane[cell + Ww]);
      float v11 = bf2f(plane[cell + Ww + 1]);
      float v = wy0*(wx0*v00 + wx1*v01) + wy1*(wx0*v10 + wx1*v11);
      pB[(size_t)(pbase + p)*128 + c] = f2bf(v);
    }
  }
}

// ---- d1/d2 norms from bf16 rows + pad-row init (deterministic, no atomics) ----
__global__ __launch_bounds__(256) void d12_k(
    ushort* __restrict__ aB, ushort* __restrict__ pB,
    float* __restrict__ d1, float* __restrict__ d2) {
  int w = threadIdx.x >> 6, l = threadIdx.x & 63;
  int base = blockIdx.x*32 + w*8;
  #pragma unroll
  for (int i = 0; i < 8; ++i) {
    int row = base + i;
    if (row < NPTS) {
      uint32_t ua = *(const uint32_t*)&aB[(size_t)row*128 + l*2];
      uint32_t up = *(const uint32_t*)&pB[(size_t)row*128 + l*2];
      float a0 = bf2f((ushort)ua), a1 = bf2f((ushort)(ua >> 16));
      float p0 = bf2f((ushort)up), p1 = bf2f((ushort)(up >> 16));
      float sa = a0*a0 + a1*a1;
      float sp = p0*p0 + p1*p1;
      for (int off = 1; off < 64; off <<= 1) {
        sa += __shfl_xor(sa, off);
        sp += __shfl_xor(sp, off);
      }
      if (l == 0) { d1[row] = sa; d2[row] = sp; }
    } else {
      *(uint32_t*)&aB[(size_t)row*128 + l*2] = 0;
      *(uint32_t*)&pB[(size_t)row*128 + l*2] = 0;
      if (l == 0) { d1[row] = 0.f; d2[row] = 1e30f; }
    }
  }
}

// ---- persistent fused GEMM: A-frags hoisted to REGISTERS, B LDS double-buffer ----
// A read once per block direct from global (16 rows x 64B = 16 full lines per
// instr). B staged via global_load_lds with XOR swizzle (linear dest,
// pre-swizzled source, XOR on read). Swapped MFMA: anchor index in lane&15.
// Per-iter LDS reads: 16 b128/lane (B only) -> MFMA-bound.
__global__ __launch_bounds__(512) void gemmp_k(
    const ushort* __restrict__ aB, const ushort* __restrict__ pB,
    const float* __restrict__ d1, const float* __restrict__ d2,
    float* __restrict__ pos, float* __restrict__ pmin) {
  __shared__ __align__(16) ushort lB[2][128*128];   // 2 x 32 KB

  // m204 bijective chunked XCD swizzle: nwg=230, q=28, r=6
  int bid = blockIdx.x;
  int xcd = bid & 7, kk = bid >> 3;
  int start = (xcd < 6) ? xcd*29 : 174 + (xcd-6)*28;
  int L = start + kk;
  int g = L / NTT, tM = L % NTT;
  int j0 = g * JPB;
  int jn = (NCT - j0 < JPB) ? (NCT - j0) : JPB;

  int tid = threadIdx.x;
  int rowg = tid >> 4, cb = (tid & 15) << 4;
  int w = tid >> 6, l = tid & 63;
  int wr = w >> 1, wc = w & 1;          // 4M x 2N waves; wave tile 64x64
  int lcol = l & 15, hq = l >> 4, rb = hq << 2;
  int rsw = (lcol & 7) << 4;

  {  // stage B0 (swizzled source, linear dest)
    const char* gB = (const char*)pB + (size_t)j0 * 128 * 256;
    #pragma unroll
    for (int rnd = 0; rnd < 4; ++rnd) {
      int row = rnd*32 + rowg;
      g2l16(gB + row*256 + (cb ^ ((row&7)<<4)), (char*)lB[0] + row*256 + cb);
    }
  }

  // hoist A fragments once: row = tM*256 + wr*64 + ma*16 + lcol
  bf16x8 aF[16];                        // [ma*4+ks], 64 VGPR
  {
    const char* gA = (const char*)aB + ((size_t)(tM*256 + wr*64 + lcol))*256 + hq*16;
    #pragma unroll
    for (int ma = 0; ma < 4; ++ma)
      #pragma unroll
      for (int ks = 0; ks < 4; ++ks)
        aF[ma*4+ks] = *(const bf16x8*)(gA + ma*16*256 + ks*64);
  }
  __syncthreads();   // drains vmcnt (B0 + aF)

  float mPart[4] = {BIGF, BIGF, BIGF, BIGF};

  for (int it = 0; it < jn; ++it) {
    int j = j0 + it;
    if (it + 1 < jn) {  // prefetch next B into alt buffer (overlaps compute)
      const char* gB = (const char*)pB + (size_t)(j+1) * 128 * 256;
      char* dst = (char*)lB[(it+1) & 1];
      #pragma unroll
      for (int rnd = 0; rnd < 4; ++rnd) {
        int row = rnd*32 + rowg;
        g2l16(gB + row*256 + (cb ^ ((row&7)<<4)), dst + row*256 + cb);
      }
    }
    const char* bufB = (const char*)lB[it & 1];
    f32x4 acc[4][4] = {};               // acc[np][ma]
    #pragma unroll
    for (int ks = 0; ks < 4; ++ks) {
      int cbase = ks*64 + (hq << 4);
      bf16x8 bF[4];
      #pragma unroll
      for (int np = 0; np < 4; ++np)
        bF[np] = *(const bf16x8*)(bufB + (wc*64 + np*16 + lcol)*256 + (cbase ^ rsw));
      #pragma unroll
      for (int np = 0; np < 4; ++np)
        #pragma unroll
        for (int ma = 0; ma < 4; ++ma)
          acc[np][ma] = __builtin_amdgcn_mfma_f32_16x16x32_bf16(bF[np], aF[ma*4+ks], acc[np][ma], 0, 0, 0);
    }

    // epilogue in t-space: t = d2[col] - 2*dot; min accumulates in mPart regs
    f32x4 d2v[4];
    #pragma unroll
    for (int np = 0; np < 4; ++np)
      d2v[np] = *(const f32x4*)&d2[j*128 + wc*64 + np*16 + rb];

    if ((j >> 1) != tM) {               // non-diagonal col-tile (uniform branch)
      #pragma unroll
      for (int ma = 0; ma < 4; ++ma)
        #pragma unroll
        for (int np = 0; np < 4; ++np)
          #pragma unroll
          for (int reg = 0; reg < 4; ++reg)
            mPart[ma] = fminf(mPart[ma], fmaf(-2.f, acc[np][ma][reg], d2v[np][reg]));
    } else {                            // diagonal-overlapping tile
      #pragma unroll
      for (int ma = 0; ma < 4; ++ma) {
        int gi = tM*256 + wr*64 + ma*16 + lcol;
        #pragma unroll
        for (int np = 0; np < 4; ++np)
          #pragma unroll
          for (int reg = 0; reg < 4; ++reg) {
            int gj = j*128 + wc*64 + np*16 + rb + reg;
            float t = fmaf(-2.f, acc[np][ma][reg], d2v[np][reg]);
            if (gi == gj)
              pos[gi] = sqrtf(fmaxf(d1[gi] + t, 0.f) + 1e-6f) + 1e-8f;
            else
              mPart[ma] = fminf(mPart[ma], t);
          }
      }
    }
    __syncthreads();                    // next buffer staged + all reads done
  }

  // final reduce: over hq via shuffles, over wc via LDS scratch; non-atomic store
  #pragma unroll
  for (int ma = 0; ma < 4; ++ma) {
    float u = mPart[ma];
    u = fminf(u, __shfl_xor(u, 16));
    u = fminf(u, __shfl_xor(u, 32));
    mPart[ma] = u;
  }
  __syncthreads();
  float* sm = (float*)lB;               // scratch [2][256]
  if (hq == 0) {
    #pragma unroll
    for (int ma = 0; ma < 4; ++ma)
      sm[wc*256 + wr*64 + ma*16 + lcol] = mPart[ma];
  }
  __syncthreads();
  if (tid < 256) {
    int row = tM*256 + tid;
    float u = fminf(sm[tid], sm[256 + tid]);
    pmin[g*NPAD + row] = sqrtf(fmaxf(d1[row] + u, 0.f) + 1e-6f) + 1e-8f;
  }
}

// -------- finalize: min over group partials (+ diag+10 cand), mean relu --------
__global__ __launch_bounds__(1024) void fin_k(const float* __restrict__ pos,
                                              const float* __restrict__ pmin,
                                              float* __restrict__ out) {
  float s = 0.f;
  for (int i = threadIdx.x; i < NPTS; i += 1024) {
    float p = pos[i];
    float mneg = p + 10.f;              // diagonal's +10-modified candidate
    #pragma unroll
    for (int g = 0; g < NG; ++g) mneg = fminf(mneg, pmin[g*NPAD + i]);
    s += fmaxf(1.0f + p - mneg, 0.f);
  }
  for (int off = 1; off < 64; off <<= 1) s += __shfl_xor(s, off);
  __shared__ float red[16];
  if ((threadIdx.x & 63) == 0) red[threadIdx.x >> 6] = s;
  __syncthreads();
  if (threadIdx.x == 0) {
    float t = 0.f;
    #pragma unroll
    for (int k = 0; k < 16; ++k) t += red[k];
    out[0] = t / (float)NPTS;
  }
}

extern "C" void kernel_launch(void* const* d_in, const int* in_sizes, int n_in,
                              void* d_out, int out_size, void* d_ws, size_t ws_size,
                              hipStream_t stream) {
  const float* feat1 = (const float*)d_in[0];
  const float* feat2 = (const float*)d_in[1];
  const float* aflow = (const float*)d_in[2];

  char* ws = (char*)d_ws;
  ushort* aB = (ushort*)ws;                                   // NPAD*128 bf16
  ushort* pB = aB + (size_t)NPAD * 128;                       // NPAD*128 bf16
  float*  d1 = (float*)(pB + (size_t)NPAD * 128);             // NPAD f32
  float*  d2 = d1 + NPAD;
  float*  pos = d2 + NPAD;
  float*  pmin = pos + NPAD;                                  // NG*NPAD f32
  u32x4*  coords = (u32x4*)(pmin + (size_t)NG*NPAD);          // NPTS u32x4

  hipLaunchKernelGGL(prep2_k, dim3(CROPB + CRDB), dim3(256), 0, stream,
                     feat1, aflow, aB, coords);
  hipLaunchKernelGGL(slab_k, dim3(1024), dim3(256), 0, stream,
                     feat2, coords, pB);
  hipLaunchKernelGGL(d12_k, dim3(NPAD/32), dim3(256), 0, stream,
                     aB, pB, d1, d2);
  hipLaunchKernelGGL(gemmp_k, dim3(NBLK), dim3(512), 0, stream,
                     aB, pB, d1, d2, pos, pmin);
  hipLaunchKernelGGL(fin_k, dim3(1), dim3(1024), 0, stream,
                     pos, pmin, (float*)d_out);
}

// Round 8
// 93.716 us; speedup vs baseline: 1.2438x; 1.0477x over previous
//
#include <hip/hip_runtime.h>
#include <stdint.h>

#define Hh 192
#define Ww 192
#define HW 36864            // 192*192
#define CROPW 38
#define CW2 1444            // 38*38
#define CROPOFF 77
#define NPTS 11552          // 8*38*38
#define NPAD 11776          // 92*128
#define NMT 92              // 128-row tiles
#define NCT 92              // 128-col tiles
#define NG 5                // col-tile groups
#define JPB 19              // col-tiles per group (last group gets 16)
#define NBLK (NG*NMT)       // 460 blocks
#define CROPB 304           // 38*8 crop blocks
#define CRDB 46             // coord blocks (46*256 >= NPTS)
#define BIGF 3.0e38f

typedef short bf16x8 __attribute__((ext_vector_type(8)));
typedef float f32x4 __attribute__((ext_vector_type(4)));
typedef uint32_t u32x2 __attribute__((ext_vector_type(2)));
typedef uint32_t u32x4 __attribute__((ext_vector_type(4)));
typedef unsigned short ushort;

__device__ __forceinline__ ushort f2bf(float f) {
  uint32_t b = __float_as_uint(f);
  uint32_t r = b + 0x7fffu + ((b >> 16) & 1u);
  return (ushort)(r >> 16);
}
__device__ __forceinline__ float bf2f(ushort u) {
  return __uint_as_float(((uint32_t)u) << 16);
}

__device__ __forceinline__ void g2l16(const void* g, void* l) {
  __builtin_amdgcn_global_load_lds(
      (const __attribute__((address_space(1))) unsigned int*)g,
      (__attribute__((address_space(3))) unsigned int*)l, 16, 0, 0);
}

// ---- prep: feat1 crop -> aB + d1;  coords + d2-zero;  pad-row init ----
__global__ __launch_bounds__(256) void prep2_k(
    const float* __restrict__ feat1, const float* __restrict__ aflow,
    ushort* __restrict__ aB, ushort* __restrict__ pB,
    float* __restrict__ d1, float* __restrict__ d2,
    u32x4* __restrict__ coords) {
  int bid = blockIdx.x;
  int t = threadIdx.x;
  if (bid < CROPB) {
    // ---------- crop row: feat1 -> aB (channel-last bf16) + d1 ----------
    __shared__ __align__(16) ushort lsh[38*136];
    int b = bid / CROPW, r = bid % CROPW;
    int y = CROPOFF + r;
    {
      int xo = t & 63, c0 = t >> 6;
      if (xo < CROPW) {
        const float* src = feat1 + ((size_t)b*128*HW) + (size_t)y*Ww + CROPOFF + xo;
        #pragma unroll
        for (int k = 0; k < 32; ++k) {
          int cc = c0*32 + k;
          lsh[xo*136 + cc] = f2bf(src[(size_t)cc*HW]);
        }
      }
    }
    __syncthreads();
    int chunk = t & 7, p0 = t >> 3;
    #pragma unroll
    for (int pp = 0; pp < 2; ++pp) {
      int p = p0 + pp*32;
      if (p >= CROPW) break;
      int idx = b*CW2 + r*CROPW + p;
      ushort* dst = aB + (size_t)idx*128 + chunk*16;
      *(bf16x8*)dst       = *(const bf16x8*)&lsh[p*136 + chunk*16];
      *(bf16x8*)(dst + 8) = *(const bf16x8*)&lsh[p*136 + chunk*16 + 8];
      float s = 0.f;
      #pragma unroll
      for (int j = 0; j < 16; ++j) {
        float v = bf2f(lsh[p*136 + chunk*16 + j]);
        s += v*v;
      }
      s += __shfl_xor(s, 1); s += __shfl_xor(s, 2); s += __shfl_xor(s, 4);
      if (chunk == 0) d1[idx] = s;
    }
  } else if (bid < CROPB + CRDB) {
    // ---------- coords + d2 zero (slab_k accumulates into d2) ----------
    int idx = (bid - CROPB)*256 + t;
    if (idx >= NPTS) return;
    d2[idx] = 0.f;
    int b = idx / CW2;
    int rem = idx % CW2;
    int r = rem / CROPW, cx = rem % CROPW;
    int y = CROPOFF + r, x = CROPOFF + cx;
    float ax = aflow[((b*2 + 0)*Hh + y)*Ww + x];
    float ay = aflow[((b*2 + 1)*Hh + y)*Ww + x];
    // replicate reference's normalize->denormalize round trip
    float gxn = ax * (2.0f/(Ww-1)) - 1.0f;
    float gyn = ay * (2.0f/(Hh-1)) - 1.0f;
    float gx = (gxn + 1.0f) * 0.5f * (Ww-1);
    float gy = (gyn + 1.0f) * 0.5f * (Hh-1);
    // clamp base cell to 190: gx==191 shifts weight to the x=191 tap (identical)
    int xi = min((int)floorf(gx), Ww-2);
    int yi = min((int)floorf(gy), Hh-2);
    u32x4 cd;
    cd.x = (uint32_t)(yi*Ww + xi);
    cd.y = __float_as_uint(gx - (float)xi);
    cd.z = __float_as_uint(gy - (float)yi);
    cd.w = 0;
    coords[idx] = cd;
  } else {
    // ---------- pad rows: zero aB/pB, d1=0, d2=big ----------
    if (t < NPAD - NPTS) {
      int row = NPTS + t;
      u32x4 z = {0,0,0,0};
      #pragma unroll
      for (int c = 0; c < 8; ++c) {
        *(u32x4*)&aB[(size_t)row*128 + c*16] = z;
        *(u32x4*)&aB[(size_t)row*128 + c*16 + 8] = z;
        *(u32x4*)&pB[(size_t)row*128 + c*16] = z;
        *(u32x4*)&pB[(size_t)row*128 + c*16 + 8] = z;
      }
      d1[row] = 0.f;
      d2[row] = 1e30f;
    }
  }
}

// ---- channel-pair slab sampler: block=(b,cpair); 2 planes in LDS u32-packed ----
__global__ __launch_bounds__(256) void slab_k(
    const float* __restrict__ feat2, const u32x4* __restrict__ coords,
    ushort* __restrict__ pB, float* __restrict__ d2) {
  __shared__ __align__(16) uint32_t plane[HW];   // 144 KB -> 1 block/CU
  int bid = blockIdx.x;
  int b = bid >> 6, cp = bid & 63, c = cp*2;
  int t = threadIdx.x;
  const float* srcA = feat2 + ((size_t)(b*128 + c)) * HW;
  const float* srcB = srcA + HW;
  #pragma unroll 6
  for (int k = 0; k < 36; ++k) {
    int i = (k*256 + t) * 4;
    f32x4 va = *(const f32x4*)(srcA + i);
    f32x4 vb = *(const f32x4*)(srcB + i);
    u32x4 pk;
    #pragma unroll
    for (int j = 0; j < 4; ++j)
      pk[j] = (uint32_t)f2bf(va[j]) | ((uint32_t)f2bf(vb[j]) << 16);
    *(u32x4*)&plane[i] = pk;
  }
  __syncthreads();
  int pbase = b*CW2;
  #pragma unroll
  for (int it = 0; it < 6; ++it) {
    int p = it*256 + t;
    if (p < CW2) {
      u32x4 cd = coords[pbase + p];
      int cell = (int)cd.x;
      float wx1 = __uint_as_float(cd.y), wx0 = 1.f - wx1;
      float wy1 = __uint_as_float(cd.z), wy0 = 1.f - wy1;
      uint32_t u00 = plane[cell];
      uint32_t u01 = plane[cell + 1];
      uint32_t u10 = plane[cell + Ww];
      uint32_t u11 = plane[cell + Ww + 1];
      float v0 = wy0*(wx0*bf2f((ushort)u00) + wx1*bf2f((ushort)u01))
               + wy1*(wx0*bf2f((ushort)u10) + wx1*bf2f((ushort)u11));
      float v1 = wy0*(wx0*bf2f((ushort)(u00>>16)) + wx1*bf2f((ushort)(u01>>16)))
               + wy1*(wx0*bf2f((ushort)(u10>>16)) + wx1*bf2f((ushort)(u11>>16)));
      ushort q0 = f2bf(v0), q1 = f2bf(v1);
      *(uint32_t*)&pB[(size_t)(pbase + p)*128 + c] = (uint32_t)q0 | ((uint32_t)q1 << 16);
      float f0 = bf2f(q0), f1 = bf2f(q1);
      atomicAdd(&d2[pbase + p], f0*f0 + f1*f1);
    }
  }
}

// ---- persistent fused GEMM: A in regs, B LDS double-buffer, 2 blocks/CU ------
// 256 thr, 4 waves (2x2), wave tile 64x64, block tile 128x128. A hoisted once
// from global. B staged via global_load_lds + XOR swizzle (linear dest,
// pre-swizzled source, XOR on read). Swapped MFMA: anchor index in lane&15.
// d2v loaded BEFORE the MFMA loop (latency hidden under MFMA).
__global__ __launch_bounds__(256) void gemmp_k(
    const ushort* __restrict__ aB, const ushort* __restrict__ pB,
    const float* __restrict__ d1, const float* __restrict__ d2,
    float* __restrict__ pos, float* __restrict__ pmin) {
  __shared__ __align__(16) ushort lB[2][128*128];   // 2 x 32 KB

  // m204 bijective chunked XCD swizzle: nwg=460, q=57, r=4
  int bid = blockIdx.x;
  int xcd = bid & 7, kk = bid >> 3;
  int start = (xcd < 4) ? xcd*58 : 232 + (xcd-4)*57;
  int L = start + kk;
  int g = L / NMT, tM = L % NMT;
  int j0 = g * JPB;
  int jn = (NCT - j0 < JPB) ? (NCT - j0) : JPB;

  int tid = threadIdx.x;
  int rowg = tid >> 4, cb = (tid & 15) << 4;
  int w = tid >> 6, l = tid & 63;
  int wr = w >> 1, wc = w & 1;          // 2M x 2N waves; wave tile 64x64
  int lcol = l & 15, hq = l >> 4, rb = hq << 2;
  int rsw = (lcol & 7) << 4;

  {  // stage B0 (swizzled source, linear dest): 128 rows x 256 B
    const char* gB = (const char*)pB + (size_t)j0 * 128 * 256;
    #pragma unroll
    for (int rnd = 0; rnd < 8; ++rnd) {
      int row = rnd*16 + rowg;
      g2l16(gB + row*256 + (cb ^ ((row&7)<<4)), (char*)lB[0] + row*256 + cb);
    }
  }

  // hoist A fragments once: row = tM*128 + wr*64 + ma*16 + lcol
  bf16x8 aF[16];                        // [ma*4+ks], 64 VGPR
  {
    const char* gA = (const char*)aB + ((size_t)(tM*128 + wr*64 + lcol))*256 + hq*16;
    #pragma unroll
    for (int ma = 0; ma < 4; ++ma)
      #pragma unroll
      for (int ks = 0; ks < 4; ++ks)
        aF[ma*4+ks] = *(const bf16x8*)(gA + ma*16*256 + ks*64);
  }
  __syncthreads();   // drains vmcnt (B0 + aF)

  float mPart[4] = {BIGF, BIGF, BIGF, BIGF};

  for (int it = 0; it < jn; ++it) {
    int j = j0 + it;
    if (it + 1 < jn) {  // prefetch next B into alt buffer (overlaps compute)
      const char* gB = (const char*)pB + (size_t)(j+1) * 128 * 256;
      char* dst = (char*)lB[(it+1) & 1];
      #pragma unroll
      for (int rnd = 0; rnd < 8; ++rnd) {
        int row = rnd*16 + rowg;
        g2l16(gB + row*256 + (cb ^ ((row&7)<<4)), dst + row*256 + cb);
      }
    }
    // d2v early: latency hides under the MFMA loop below
    f32x4 d2v[4];
    #pragma unroll
    for (int np = 0; np < 4; ++np)
      d2v[np] = *(const f32x4*)&d2[j*128 + wc*64 + np*16 + rb];

    const char* bufB = (const char*)lB[it & 1];
    f32x4 acc[4][4] = {};               // acc[np][ma]
    #pragma unroll
    for (int ks = 0; ks < 4; ++ks) {
      int cbase = ks*64 + (hq << 4);
      bf16x8 bF[4];
      #pragma unroll
      for (int np = 0; np < 4; ++np)
        bF[np] = *(const bf16x8*)(bufB + (wc*64 + np*16 + lcol)*256 + (cbase ^ rsw));
      #pragma unroll
      for (int np = 0; np < 4; ++np)
        #pragma unroll
        for (int ma = 0; ma < 4; ++ma)
          acc[np][ma] = __builtin_amdgcn_mfma_f32_16x16x32_bf16(bF[np], aF[ma*4+ks], acc[np][ma], 0, 0, 0);
    }

    // epilogue in t-space: t = d2[col] - 2*dot; min accumulates in mPart regs
    if (j != tM) {                      // non-diagonal col-tile (uniform branch)
      #pragma unroll
      for (int ma = 0; ma < 4; ++ma)
        #pragma unroll
        for (int np = 0; np < 4; ++np)
          #pragma unroll
          for (int reg = 0; reg < 4; ++reg)
            mPart[ma] = fminf(mPart[ma], fmaf(-2.f, acc[np][ma][reg], d2v[np][reg]));
    } else {                            // diagonal tile
      #pragma unroll
      for (int ma = 0; ma < 4; ++ma) {
        int gi = tM*128 + wr*64 + ma*16 + lcol;
        #pragma unroll
        for (int np = 0; np < 4; ++np)
          #pragma unroll
          for (int reg = 0; reg < 4; ++reg) {
            int gj = j*128 + wc*64 + np*16 + rb + reg;
            float t = fmaf(-2.f, acc[np][ma][reg], d2v[np][reg]);
            if (gi == gj)
              pos[gi] = sqrtf(fmaxf(d1[gi] + t, 0.f) + 1e-6f) + 1e-8f;
            else
              mPart[ma] = fminf(mPart[ma], t);
          }
      }
    }
    __syncthreads();                    // next buffer staged + all reads done
  }

  // final reduce: over hq via shuffles, over wc via LDS scratch; non-atomic store
  #pragma unroll
  for (int ma = 0; ma < 4; ++ma) {
    float u = mPart[ma];
    u = fminf(u, __shfl_xor(u, 16));
    u = fminf(u, __shfl_xor(u, 32));
    mPart[ma] = u;
  }
  __syncthreads();
  float* sm = (float*)lB;               // scratch [2][128]
  if (hq == 0) {
    #pragma unroll
    for (int ma = 0; ma < 4; ++ma)
      sm[wc*128 + wr*64 + ma*16 + lcol] = mPart[ma];
  }
  __syncthreads();
  if (tid < 128) {
    int row = tM*128 + tid;
    float u = fminf(sm[tid], sm[128 + tid]);
    pmin[g*NPAD + row] = sqrtf(fmaxf(d1[row] + u, 0.f) + 1e-6f) + 1e-8f;
  }
}

// -------- finalize: min over group partials (+ diag+10 cand), mean relu --------
__global__ __launch_bounds__(1024) void fin_k(const float* __restrict__ pos,
                                              const float* __restrict__ pmin,
                                              float* __restrict__ out) {
  float s = 0.f;
  for (int i = threadIdx.x; i < NPTS; i += 1024) {
    float p = pos[i];
    float mneg = p + 10.f;              // diagonal's +10-modified candidate
    #pragma unroll
    for (int g = 0; g < NG; ++g) mneg = fminf(mneg, pmin[g*NPAD + i]);
    s += fmaxf(1.0f + p - mneg, 0.f);
  }
  for (int off = 1; off < 64; off <<= 1) s += __shfl_xor(s, off);
  __shared__ float red[16];
  if ((threadIdx.x & 63) == 0) red[threadIdx.x >> 6] = s;
  __syncthreads();
  if (threadIdx.x == 0) {
    float t = 0.f;
    #pragma unroll
    for (int k = 0; k < 16; ++k) t += red[k];
    out[0] = t / (float)NPTS;
  }
}

extern "C" void kernel_launch(void* const* d_in, const int* in_sizes, int n_in,
                              void* d_out, int out_size, void* d_ws, size_t ws_size,
                              hipStream_t stream) {
  const float* feat1 = (const float*)d_in[0];
  const float* feat2 = (const float*)d_in[1];
  const float* aflow = (const float*)d_in[2];

  char* ws = (char*)d_ws;
  ushort* aB = (ushort*)ws;                                   // NPAD*128 bf16
  ushort* pB = aB + (size_t)NPAD * 128;                       // NPAD*128 bf16
  float*  d1 = (float*)(pB + (size_t)NPAD * 128);             // NPAD f32
  float*  d2 = d1 + NPAD;
  float*  pos = d2 + NPAD;
  float*  pmin = pos + NPAD;                                  // NG*NPAD f32
  u32x4*  coords = (u32x4*)(pmin + (size_t)NG*NPAD);          // NPTS u32x4

  hipLaunchKernelGGL(prep2_k, dim3(CROPB + CRDB + 1), dim3(256), 0, stream,
                     feat1, aflow, aB, pB, d1, d2, coords);
  hipLaunchKernelGGL(slab_k, dim3(512), dim3(256), 0, stream,
                     feat2, coords, pB, d2);
  hipLaunchKernelGGL(gemmp_k, dim3(NBLK), dim3(256), 0, stream,
                     aB, pB, d1, d2, pos, pmin);
  hipLaunchKernelGGL(fin_k, dim3(1), dim3(1024), 0, stream,
                     pos, pmin, (float*)d_out);
}

// Round 9
// 89.963 us; speedup vs baseline: 1.2957x; 1.0417x over previous
//
#include <hip/hip_runtime.h>
#include <stdint.h>

#define Hh 192
#define Ww 192
#define HW 36864            // 192*192
#define CROPW 38
#define CW2 1444            // 38*38
#define CROPOFF 77
#define NPTS 11552          // 8*38*38
#define NPAD 11776          // 92*128
#define NMT 92              // 128-row tiles
#define NCT 92              // 128-col tiles
#define NG 5                // col-tile groups
#define JPB 19              // col-tiles per group (last group gets 16)
#define NBLK (NG*NMT)       // 460 blocks
#define SLABB 512           // 8 b * 64 channel-pairs
#define CROPB 304           // 38*8 crop blocks
#define BIGF 3.0e38f

typedef short bf16x8 __attribute__((ext_vector_type(8)));
typedef float f32x4 __attribute__((ext_vector_type(4)));
typedef uint32_t u32x4 __attribute__((ext_vector_type(4)));
typedef unsigned short ushort;

__device__ __forceinline__ ushort f2bf(float f) {
  uint32_t b = __float_as_uint(f);
  uint32_t r = b + 0x7fffu + ((b >> 16) & 1u);
  return (ushort)(r >> 16);
}
__device__ __forceinline__ float bf2f(ushort u) {
  return __uint_as_float(((uint32_t)u) << 16);
}

__device__ __forceinline__ void g2l16(const void* g, void* l) {
  __builtin_amdgcn_global_load_lds(
      (const __attribute__((address_space(1))) unsigned int*)g,
      (__attribute__((address_space(3))) unsigned int*)l, 16, 0, 0);
}

// ---- fused sampler: slab blocks (feat2->pB,d2) + crop blocks (feat1->aB,d1) ----
// 1024 threads. Slab: channel-pair plane staged to LDS u32-packed (144 KB,
// 16 waves = 4/SIMD for latency hiding), coords computed inline from aflow.
// d2 accumulated via atomicAdd (zeroed by memset before this dispatch).
__global__ __launch_bounds__(1024) void fused_k(
    const float* __restrict__ feat1, const float* __restrict__ feat2,
    const float* __restrict__ aflow,
    ushort* __restrict__ aB, ushort* __restrict__ pB,
    float* __restrict__ d1, float* __restrict__ d2) {
  __shared__ __align__(16) uint32_t plane[HW];   // 144 KB (slab) / reused by crop
  int bid = blockIdx.x;
  int t = threadIdx.x;

  if (bid < SLABB) {
    // ---------------- slab: (b, channel-pair) ----------------
    int b = bid >> 6, c = (bid & 63) * 2;
    const float* srcA = feat2 + ((size_t)(b*128 + c)) * HW;
    const float* srcB = srcA + HW;
    #pragma unroll
    for (int k = 0; k < 9; ++k) {
      int i = (k*1024 + t) * 4;
      f32x4 va = *(const f32x4*)(srcA + i);
      f32x4 vb = *(const f32x4*)(srcB + i);
      u32x4 pk;
      #pragma unroll
      for (int j = 0; j < 4; ++j)
        pk[j] = (uint32_t)f2bf(va[j]) | ((uint32_t)f2bf(vb[j]) << 16);
      *(u32x4*)&plane[i] = pk;
    }
    __syncthreads();
    int pbase = b*CW2;
    #pragma unroll
    for (int it = 0; it < 2; ++it) {
      int p = it*1024 + t;
      if (p < CW2) {
        int r = p / CROPW, cx = p % CROPW;
        int y = CROPOFF + r, x = CROPOFF + cx;
        float ax = aflow[((b*2 + 0)*Hh + y)*Ww + x];
        float ay = aflow[((b*2 + 1)*Hh + y)*Ww + x];
        // replicate reference's normalize->denormalize round trip
        float gxn = ax * (2.0f/(Ww-1)) - 1.0f;
        float gyn = ay * (2.0f/(Hh-1)) - 1.0f;
        float gx = (gxn + 1.0f) * 0.5f * (Ww-1);
        float gy = (gyn + 1.0f) * 0.5f * (Hh-1);
        // clamp base cell to 190: gx==191 shifts weight to the x=191 tap
        int xi = min((int)floorf(gx), Ww-2);
        int yi = min((int)floorf(gy), Hh-2);
        float wx1 = gx - (float)xi, wx0 = 1.f - wx1;
        float wy1 = gy - (float)yi, wy0 = 1.f - wy1;
        int cell = yi*Ww + xi;
        uint32_t u00 = plane[cell];
        uint32_t u01 = plane[cell + 1];
        uint32_t u10 = plane[cell + Ww];
        uint32_t u11 = plane[cell + Ww + 1];
        float v0 = wy0*(wx0*bf2f((ushort)u00) + wx1*bf2f((ushort)u01))
                 + wy1*(wx0*bf2f((ushort)u10) + wx1*bf2f((ushort)u11));
        float v1 = wy0*(wx0*bf2f((ushort)(u00>>16)) + wx1*bf2f((ushort)(u01>>16)))
                 + wy1*(wx0*bf2f((ushort)(u10>>16)) + wx1*bf2f((ushort)(u11>>16)));
        ushort q0 = f2bf(v0), q1 = f2bf(v1);
        *(uint32_t*)&pB[(size_t)(pbase + p)*128 + c] = (uint32_t)q0 | ((uint32_t)q1 << 16);
        float f0 = bf2f(q0), f1 = bf2f(q1);
        atomicAdd(&d2[pbase + p], f0*f0 + f1*f1);
      }
    }
  } else if (bid < SLABB + CROPB) {
    // ---------------- crop row: feat1 -> aB (channel-last bf16) + d1 ----------
    ushort* lsh = (ushort*)plane;       // 38*136 ushorts
    int rb2 = bid - SLABB;
    int b = rb2 / CROPW, r = rb2 % CROPW;
    int y = CROPOFF + r;
    {
      int xo = t & 63, cg = t >> 6;     // 38 active lanes; 16 groups x 8 ch
      if (xo < CROPW) {
        const float* src = feat1 + ((size_t)b*128*HW) + (size_t)y*Ww + CROPOFF + xo;
        #pragma unroll
        for (int k = 0; k < 8; ++k) {
          int cc = cg + k*16;
          lsh[xo*136 + cc] = f2bf(src[(size_t)cc*HW]);
        }
      }
    }
    __syncthreads();
    int chunk = t & 7, p = t >> 3;      // 128 p-slots, 38 active
    if (p < CROPW) {
      int idx = b*CW2 + r*CROPW + p;
      ushort* dst = aB + (size_t)idx*128 + chunk*16;
      *(bf16x8*)dst       = *(const bf16x8*)&lsh[p*136 + chunk*16];
      *(bf16x8*)(dst + 8) = *(const bf16x8*)&lsh[p*136 + chunk*16 + 8];
      float s = 0.f;
      #pragma unroll
      for (int j = 0; j < 16; ++j) {
        float v = bf2f(lsh[p*136 + chunk*16 + j]);
        s += v*v;
      }
      s += __shfl_xor(s, 1); s += __shfl_xor(s, 2); s += __shfl_xor(s, 4);
      if (chunk == 0) d1[idx] = s;
    }
  } else {
    // ---------------- pad rows: zero aB/pB, d1=0, d2=big ----------------
    if (t < NPAD - NPTS) {
      int row = NPTS + t;
      u32x4 z = {0,0,0,0};
      #pragma unroll
      for (int c = 0; c < 8; ++c) {
        *(u32x4*)&aB[(size_t)row*128 + c*16] = z;
        *(u32x4*)&aB[(size_t)row*128 + c*16 + 8] = z;
        *(u32x4*)&pB[(size_t)row*128 + c*16] = z;
        *(u32x4*)&pB[(size_t)row*128 + c*16 + 8] = z;
      }
      d1[row] = 0.f;
      d2[row] = 1e30f;
    }
  }
}

// ---- persistent fused GEMM: A in regs, B LDS double-buffer, 2 blocks/CU ------
// 256 thr, 4 waves (2x2), wave tile 64x64, block tile 128x128. A hoisted once
// from global. B staged via global_load_lds + XOR swizzle (linear dest,
// pre-swizzled source, XOR on read). Swapped MFMA: anchor index in lane&15.
__global__ __launch_bounds__(256) void gemmp_k(
    const ushort* __restrict__ aB, const ushort* __restrict__ pB,
    const float* __restrict__ d1, const float* __restrict__ d2,
    float* __restrict__ pos, float* __restrict__ pmin) {
  __shared__ __align__(16) ushort lB[2][128*128];   // 2 x 32 KB

  // m204 bijective chunked XCD swizzle: nwg=460, q=57, r=4
  int bid = blockIdx.x;
  int xcd = bid & 7, kk = bid >> 3;
  int start = (xcd < 4) ? xcd*58 : 232 + (xcd-4)*57;
  int L = start + kk;
  int g = L / NMT, tM = L % NMT;
  int j0 = g * JPB;
  int jn = (NCT - j0 < JPB) ? (NCT - j0) : JPB;

  int tid = threadIdx.x;
  int rowg = tid >> 4, cb = (tid & 15) << 4;
  int w = tid >> 6, l = tid & 63;
  int wr = w >> 1, wc = w & 1;          // 2M x 2N waves; wave tile 64x64
  int lcol = l & 15, hq = l >> 4, rb = hq << 2;
  int rsw = (lcol & 7) << 4;

  {  // stage B0 (swizzled source, linear dest): 128 rows x 256 B
    const char* gB = (const char*)pB + (size_t)j0 * 128 * 256;
    #pragma unroll
    for (int rnd = 0; rnd < 8; ++rnd) {
      int row = rnd*16 + rowg;
      g2l16(gB + row*256 + (cb ^ ((row&7)<<4)), (char*)lB[0] + row*256 + cb);
    }
  }

  // hoist A fragments once: row = tM*128 + wr*64 + ma*16 + lcol
  bf16x8 aF[16];                        // [ma*4+ks], 64 VGPR
  {
    const char* gA = (const char*)aB + ((size_t)(tM*128 + wr*64 + lcol))*256 + hq*16;
    #pragma unroll
    for (int ma = 0; ma < 4; ++ma)
      #pragma unroll
      for (int ks = 0; ks < 4; ++ks)
        aF[ma*4+ks] = *(const bf16x8*)(gA + ma*16*256 + ks*64);
  }
  __syncthreads();   // drains vmcnt (B0 + aF)

  float mPart[4] = {BIGF, BIGF, BIGF, BIGF};

  for (int it = 0; it < jn; ++it) {
    int j = j0 + it;
    if (it + 1 < jn) {  // prefetch next B into alt buffer (overlaps compute)
      const char* gB = (const char*)pB + (size_t)(j+1) * 128 * 256;
      char* dst = (char*)lB[(it+1) & 1];
      #pragma unroll
      for (int rnd = 0; rnd < 8; ++rnd) {
        int row = rnd*16 + rowg;
        g2l16(gB + row*256 + (cb ^ ((row&7)<<4)), dst + row*256 + cb);
      }
    }
    // d2v early: latency hides under the MFMA loop below
    f32x4 d2v[4];
    #pragma unroll
    for (int np = 0; np < 4; ++np)
      d2v[np] = *(const f32x4*)&d2[j*128 + wc*64 + np*16 + rb];

    const char* bufB = (const char*)lB[it & 1];
    f32x4 acc[4][4] = {};               // acc[np][ma]
    #pragma unroll
    for (int ks = 0; ks < 4; ++ks) {
      int cbase = ks*64 + (hq << 4);
      bf16x8 bF[4];
      #pragma unroll
      for (int np = 0; np < 4; ++np)
        bF[np] = *(const bf16x8*)(bufB + (wc*64 + np*16 + lcol)*256 + (cbase ^ rsw));
      #pragma unroll
      for (int np = 0; np < 4; ++np)
        #pragma unroll
        for (int ma = 0; ma < 4; ++ma)
          acc[np][ma] = __builtin_amdgcn_mfma_f32_16x16x32_bf16(bF[np], aF[ma*4+ks], acc[np][ma], 0, 0, 0);
    }

    // epilogue in t-space: t = d2[col] - 2*dot; min accumulates in mPart regs
    if (j != tM) {                      // non-diagonal col-tile (uniform branch)
      #pragma unroll
      for (int ma = 0; ma < 4; ++ma)
        #pragma unroll
        for (int np = 0; np < 4; ++np)
          #pragma unroll
          for (int reg = 0; reg < 4; ++reg)
            mPart[ma] = fminf(mPart[ma], fmaf(-2.f, acc[np][ma][reg], d2v[np][reg]));
    } else {                            // diagonal tile
      #pragma unroll
      for (int ma = 0; ma < 4; ++ma) {
        int gi = tM*128 + wr*64 + ma*16 + lcol;
        #pragma unroll
        for (int np = 0; np < 4; ++np)
          #pragma unroll
          for (int reg = 0; reg < 4; ++reg) {
            int gj = j*128 + wc*64 + np*16 + rb + reg;
            float t = fmaf(-2.f, acc[np][ma][reg], d2v[np][reg]);
            if (gi == gj)
              pos[gi] = sqrtf(fmaxf(d1[gi] + t, 0.f) + 1e-6f) + 1e-8f;
            else
              mPart[ma] = fminf(mPart[ma], t);
          }
      }
    }
    __syncthreads();                    // next buffer staged + all reads done
  }

  // final reduce: over hq via shuffles, over wc via LDS scratch; non-atomic store
  #pragma unroll
  for (int ma = 0; ma < 4; ++ma) {
    float u = mPart[ma];
    u = fminf(u, __shfl_xor(u, 16));
    u = fminf(u, __shfl_xor(u, 32));
    mPart[ma] = u;
  }
  __syncthreads();
  float* sm = (float*)lB;               // scratch [2][128]
  if (hq == 0) {
    #pragma unroll
    for (int ma = 0; ma < 4; ++ma)
      sm[wc*128 + wr*64 + ma*16 + lcol] = mPart[ma];
  }
  __syncthreads();
  if (tid < 128) {
    int row = tM*128 + tid;
    float u = fminf(sm[tid], sm[128 + tid]);
    pmin[g*NPAD + row] = sqrtf(fmaxf(d1[row] + u, 0.f) + 1e-6f) + 1e-8f;
  }
}

// -------- finalize: min over group partials (+ diag+10 cand), mean relu --------
__global__ __launch_bounds__(1024) void fin_k(const float* __restrict__ pos,
                                              const float* __restrict__ pmin,
                                              float* __restrict__ out) {
  float s = 0.f;
  for (int i = threadIdx.x; i < NPTS; i += 1024) {
    float p = pos[i];
    float mneg = p + 10.f;              // diagonal's +10-modified candidate
    #pragma unroll
    for (int g = 0; g < NG; ++g) mneg = fminf(mneg, pmin[g*NPAD + i]);
    s += fmaxf(1.0f + p - mneg, 0.f);
  }
  for (int off = 1; off < 64; off <<= 1) s += __shfl_xor(s, off);
  __shared__ float red[16];
  if ((threadIdx.x & 63) == 0) red[threadIdx.x >> 6] = s;
  __syncthreads();
  if (threadIdx.x == 0) {
    float t = 0.f;
    #pragma unroll
    for (int k = 0; k < 16; ++k) t += red[k];
    out[0] = t / (float)NPTS;
  }
}

extern "C" void kernel_launch(void* const* d_in, const int* in_sizes, int n_in,
                              void* d_out, int out_size, void* d_ws, size_t ws_size,
                              hipStream_t stream) {
  const float* feat1 = (const float*)d_in[0];
  const float* feat2 = (const float*)d_in[1];
  const float* aflow = (const float*)d_in[2];

  char* ws = (char*)d_ws;
  ushort* aB = (ushort*)ws;                                   // NPAD*128 bf16
  ushort* pB = aB + (size_t)NPAD * 128;                       // NPAD*128 bf16
  float*  d1 = (float*)(pB + (size_t)NPAD * 128);             // NPAD f32
  float*  d2 = d1 + NPAD;
  float*  pos = d2 + NPAD;
  float*  pmin = pos + NPAD;                                  // NG*NPAD f32

  hipMemsetAsync(d2, 0, NPTS * sizeof(float), stream);        // slab atomics base
  hipLaunchKernelGGL(fused_k, dim3(SLABB + CROPB + 1), dim3(1024), 0, stream,
                     feat1, feat2, aflow, aB, pB, d1, d2);
  hipLaunchKernelGGL(gemmp_k, dim3(NBLK), dim3(256), 0, stream,
                     aB, pB, d1, d2, pos, pmin);
  hipLaunchKernelGGL(fin_k, dim3(1), dim3(1024), 0, stream,
                     pos, pmin, (float*)d_out);
}